// Round 5
// baseline (63.292 us; speedup 1.0000x reference)
//
#include <hip/hip_runtime.h>
#include <limits.h>

// Problem constants (fixed by setup_inputs):
//   xyz (B,N,3) f32, new_xyz (B,P,3) f32, features (B,C,N) f32
//   out = concat([grouped_xyz - center, grouped_features], ch) -> (B, 3+C, P, S)
#define BB 2
#define NN 16384
#define PP 4096
#define CC 64
#define SS 32
#define R2 0.01f
#define OUTCH (3 + CC)
#define GRES 10
#define NCELL 1000  // 10x10x10, cell size 0.1 == radius

__device__ __forceinline__ int cell_of(float v) {
  int q = (int)(v * 10.0f);  // v in [0,1): floor
  return q < 0 ? 0 : (q > GRES - 1 ? GRES - 1 : q);
}
__device__ __forceinline__ int cell_clamp_floor(float v) {
  int q = (int)floorf(v * 10.0f);
  return q < 0 ? 0 : (q > GRES - 1 ? GRES - 1 : q);
}

// --------------------------------------------------------------------------
// Fused binning: one block per batch (1024 threads, 16 pts/thread).
// LDS histogram -> LDS shfl-scan (2 barriers) -> scatter with LDS fill
// counters. Emits global CSR cellStart[] and sorted4[] = (x,y,z,idx_bits).
// Within-cell order is atomic-arrival (nondeterministic) but downstream
// output depends only on the SET of in-ball indices (bitmap) => determinism.
// --------------------------------------------------------------------------
__global__ __launch_bounds__(1024) void bin_kernel(
    const float* __restrict__ xyz, int* __restrict__ cellStartG,
    float4* __restrict__ sorted4) {
  __shared__ int hist[NCELL];
  __shared__ int fill[NCELL];
  __shared__ int cstart[NCELL];
  __shared__ int wtot[16];
  const int b = blockIdx.x;
  const int t = threadIdx.x;
  const int lane = t & 63;
  const int w = t >> 6;

  if (t < NCELL) { hist[t] = 0; fill[t] = 0; }
  __syncthreads();

  const float* __restrict__ xb = xyz + (size_t)b * NN * 3;
  int cells[16];
#pragma unroll
  for (int k = 0; k < 16; ++k) {
    const int i = t + k * 1024;
    const float x = xb[i * 3 + 0];
    const float y = xb[i * 3 + 1];
    const float z = xb[i * 3 + 2];
    const int c = (cell_of(z) * GRES + cell_of(y)) * GRES + cell_of(x);
    cells[k] = c;
    atomicAdd(&hist[c], 1);
  }
  __syncthreads();

  // exclusive scan over 1000 cells (threads 0..999; others add zeros)
  const int own = (t < NCELL) ? hist[t] : 0;
  int incl = own;
#pragma unroll
  for (int d = 1; d < 64; d <<= 1) {
    const int v = __shfl_up(incl, d);
    if (lane >= d) incl += v;
  }
  if (lane == 63) wtot[w] = incl;
  __syncthreads();
  int pre = 0;
#pragma unroll
  for (int k = 0; k < 16; ++k) pre += (k < w) ? wtot[k] : 0;
  const int excl = pre + incl - own;
  if (t < NCELL) {
    cstart[t] = excl;
    cellStartG[b * 1001 + t] = excl;
  }
  if (t == 0) cellStartG[b * 1001 + NCELL] = NN;
  __syncthreads();

#pragma unroll
  for (int k = 0; k < 16; ++k) {
    const int i = t + k * 1024;
    const float x = xb[i * 3 + 0];
    const float y = xb[i * 3 + 1];
    const float z = xb[i * 3 + 2];
    const int c = cells[k];
    const int r = atomicAdd(&fill[c], 1);
    float4 v;
    v.x = x; v.y = y; v.z = z; v.w = __int_as_float(i);
    sorted4[(size_t)b * NN + cstart[c] + r] = v;
  }
}

// --------------------------------------------------------------------------
// Ball query v5: one wave per query. The <=9 CSR row-ranges of the ball's
// cell box are FLATTENED: lanes 0..nr-1 prefetch (start,len) in parallel, a
// 4-step shfl scan concatenates them into one candidate space [0,T), and the
// main loop runs ceil(T/64) fully-packed iterations. g -> (range,offset) via
// an unrolled select ladder (constant indices only -> stays in registers).
// In-ball original indices are marked in a per-wave 16384-bit LDS bitmap
// (9-word padded stripes => conflict-free); popcount + shfl-scan emits the
// first SS in ascending index order. Box margin +1e-5 can only ADD candidates
// (each still exactly tested); d2 test matches numpy bit-exactly
// (fp contract off, (dx^2+dy^2)+dz^2 order).
// --------------------------------------------------------------------------
__global__ __launch_bounds__(256) void ball_query_grid(
    const float4* __restrict__ sorted4, const int* __restrict__ cellStart,
    const float* __restrict__ new_xyz, int* __restrict__ idx_out) {
#pragma clang fp contract(off)
  __shared__ unsigned bmAll[4 * 576];  // 4 waves x (512 words padded to 64*9)
  const int widx = threadIdx.x >> 6;
  const int lane = threadIdx.x & 63;
  const int wave = blockIdx.x * 4 + widx;
  const int b = wave >> 12;  // PP = 4096
  unsigned* bm = bmAll + widx * 576;

  const float cx = new_xyz[wave * 3 + 0];
  const float cy = new_xyz[wave * 3 + 1];
  const float cz = new_xyz[wave * 3 + 2];
  const float4* __restrict__ sb = sorted4 + (size_t)b * NN;
  const int* __restrict__ csb = cellStart + b * 1001;
  int* __restrict__ myout = idx_out + wave * SS;

#pragma unroll
  for (int k = 0; k < 9; ++k) bm[k * 64 + lane] = 0;

  const float mg = 0.1f + 1e-5f;
  const int lox = cell_clamp_floor(cx - mg), hix = cell_clamp_floor(cx + mg);
  const int loy = cell_clamp_floor(cy - mg), hiy = cell_clamp_floor(cy + mg);
  const int loz = cell_clamp_floor(cz - mg), hiz = cell_clamp_floor(cz + mg);
  const int nx = hix - lox + 1;
  const int ny = hiy - loy + 1;
  const int nz = hiz - loz + 1;
  const int nr = nz * ny;  // 1..9 row-ranges

  // lanes 0..nr-1 fetch their range bounds in parallel
  int s_l = 0, len_l = 0;
  if (lane < nr) {
    int zi, yi;
    if (ny == 1) { zi = lane; yi = 0; }
    else if (ny == 2) { zi = lane >> 1; yi = lane & 1; }
    else { zi = (lane * 11) >> 5; yi = lane - zi * 3; }  // lane/3, lane<9
    const int c0 = ((loz + zi) * GRES + (loy + yi)) * GRES + lox;
    s_l = csb[c0];
    len_l = csb[c0 + nx] - s_l;
  }
  // 4-step scan covers lanes < 16 fully; lanes >= nr contribute len 0
  int incl = len_l;
#pragma unroll
  for (int d = 1; d <= 8; d <<= 1) {
    const int v = __shfl_up(incl, d);
    if (lane >= d) incl += v;
  }
  const int T = __shfl(incl, nr - 1);  // total candidates
  const int Lx = incl - len_l;         // exclusive offset of this range

  int Lk[9], Sk[9];
#pragma unroll
  for (int k = 0; k < 9; ++k) {  // Lk[k] == T for k >= nr
    Lk[k] = __shfl(Lx, k);
    Sk[k] = __shfl(s_l, k);
  }

  for (int t0 = 0; t0 < T; t0 += 64) {
    const int g = t0 + lane;
    if (g < T) {
      int L = Lk[0], S = Sk[0];
#pragma unroll
      for (int k = 1; k < 9; ++k) {
        const bool cge = g >= Lk[k];
        L = cge ? Lk[k] : L;
        S = cge ? Sk[k] : S;
      }
      const float4 pt = sb[S + (g - L)];
      const float dx = cx - pt.x;
      const float dy = cy - pt.y;
      const float dz = cz - pt.z;
      const float a = dx * dx + dy * dy;
      const float d2 = a + dz * dz;
      if (d2 < R2) {
        const int orig = __float_as_int(pt.w);
        const int wi = orig >> 5;  // word 0..511
        atomicOr(&bm[(wi >> 3) * 9 + (wi & 7)], 1u << (orig & 31));
      }
    }
  }
  __threadfence_block();  // drain LDS atomics before the scan reads

  // Scan: lane l owns words [8l,8l+8) = orig indices [256l, 256l+256).
  unsigned wv[8];
  int c = 0;
  int fi = INT_MAX;
#pragma unroll
  for (int k = 0; k < 8; ++k) {
    wv[k] = bm[lane * 9 + k];
    c += (int)__popc(wv[k]);
    if (fi == INT_MAX && wv[k])
      fi = lane * 256 + k * 32 + (int)__builtin_ctz(wv[k]);
  }

  int incl2 = c;
#pragma unroll
  for (int d = 1; d < 64; d <<= 1) {
    const int t = __shfl_up(incl2, d);
    if (lane >= d) incl2 += t;
  }
  const int E = incl2 - c;               // exclusive prefix
  const int total = __shfl(incl2, 63);   // wave total in-ball count

  const unsigned long long nb = __ballot(c > 0);
  int fc = 0;
  if (nb) fc = __shfl(fi, (int)__builtin_ctzll(nb));

  int s = E;
  if (s < SS) {
#pragma unroll
    for (int k = 0; k < 8; ++k) {
      unsigned ww = wv[k];
      while (ww && s < SS) {
        const int bpos = (int)__builtin_ctz(ww);
        ww &= ww - 1;
        myout[s++] = lane * 256 + k * 32 + bpos;
      }
      if (s >= SS) break;
    }
  }
  for (int s2 = total + lane; s2 < SS; s2 += 64) myout[s2] = fc;
}

// --------------------------------------------------------------------------
// Transpose features (B,C,N) -> (B,N,C): gathers then read full 256B rows.
// --------------------------------------------------------------------------
__global__ __launch_bounds__(256) void transpose_feat_kernel(
    const float* __restrict__ feat, float* __restrict__ featT) {
  __shared__ float tile[64][65];
  const int n0 = blockIdx.x * 64;
  const int b = blockIdx.y;
  const int jn = threadIdx.x & 63;
  const int g4 = threadIdx.x >> 6;

  const float* fb = feat + (size_t)b * CC * NN;
#pragma unroll
  for (int k = 0; k < 16; ++k) {
    const int c = g4 * 16 + k;
    tile[c][jn] = fb[(size_t)c * NN + n0 + jn];
  }
  __syncthreads();
  float* ft = featT + ((size_t)b * NN + n0) * CC;
#pragma unroll
  for (int k = 0; k < 16; ++k) {
    const int j = g4 * 16 + k;
    ft[(size_t)j * CC + jn] = tile[jn][j];
  }
}

// --------------------------------------------------------------------------
// Gather + group via LDS staging (TILE=128 samples/block), coalesced stores.
// --------------------------------------------------------------------------
#define TILE 128
__global__ __launch_bounds__(256) void group_kernel_t(
    const float* __restrict__ xyz, const float* __restrict__ new_xyz,
    const float* __restrict__ featT, const int* __restrict__ idx,
    float* __restrict__ out) {
  __shared__ float lds[TILE * 65];
  const int base = blockIdx.x * TILE;
  const int b = base >> 17;  // P*S = 2^17
  const int t = threadIdx.x;
  const size_t PS = (size_t)PP * SS;

  const float4* ftb = (const float4*)(featT + (size_t)b * NN * CC);
#pragma unroll
  for (int k = 0; k < 8; ++k) {
    const int u = k * 256 + t;
    const int r = u >> 4;
    const int q = u & 15;
    const int v = idx[base + r];
    const float4 val = ftb[(size_t)v * 16 + q];
    float* dst = &lds[r * 65 + q * 4];
    dst[0] = val.x; dst[1] = val.y; dst[2] = val.z; dst[3] = val.w;
  }
  __syncthreads();

  if (t < TILE) {
    const int g = base + t;
    const int v = idx[g];
    const int p = (g >> 5) & (PP - 1);
    const float* xr = xyz + ((size_t)b * NN + v) * 3;
    const float* cr = new_xyz + (size_t)(b * PP + p) * 3;
    const size_t ob = (size_t)b * OUTCH * PS + ((size_t)g & (PS - 1));
    out[ob + 0 * PS] = xr[0] - cr[0];
    out[ob + 1 * PS] = xr[1] - cr[1];
    out[ob + 2 * PS] = xr[2] - cr[2];
  }

  float* ob3 = out + (size_t)b * OUTCH * PS + 3 * PS + ((size_t)base & (PS - 1));
#pragma unroll
  for (int k = 0; k < 32; ++k) {
    const int u = k * 256 + t;
    const int c = u >> 7;
    const int r = u & 127;
    ob3[(size_t)c * PS + r] = lds[r * 65 + c];
  }
}

extern "C" void kernel_launch(void* const* d_in, const int* in_sizes, int n_in,
                              void* d_out, int out_size, void* d_ws, size_t ws_size,
                              hipStream_t stream) {
  const float* xyz = (const float*)d_in[0];
  const float* new_xyz = (const float*)d_in[1];
  const float* feat = (const float*)d_in[2];
  float* out = (float*)d_out;

  // ws layout: [idx 1MB][featT 8.39MB]; the binning region ALIASES featT
  // (binning + ball query complete before transpose writes featT; all
  // kernels are stream-serialized, so the overlap is dead by then).
  const size_t idxBytes = (size_t)BB * PP * SS * sizeof(int);
  int* idx = (int*)d_ws;
  char* ovl = (char*)d_ws + idxBytes;
  float* featT = (float*)ovl;
  float4* sorted4 = (float4*)ovl;                                   // 524288 B
  int* cellStart = (int*)(ovl + (size_t)BB * NN * sizeof(float4));  // 8008 B

  bin_kernel<<<BB, 1024, 0, stream>>>(xyz, cellStart, sorted4);
  ball_query_grid<<<(BB * PP) / 4, 256, 0, stream>>>(sorted4, cellStart, new_xyz, idx);
  transpose_feat_kernel<<<dim3(NN / 64, BB), 256, 0, stream>>>(feat, featT);
  group_kernel_t<<<(BB * PP * SS) / TILE, 256, 0, stream>>>(xyz, new_xyz, featT,
                                                            idx, out);
}

// Round 6
// 61.058 us; speedup vs baseline: 1.0366x; 1.0366x over previous
//
#include <hip/hip_runtime.h>
#include <limits.h>

// Problem constants (fixed by setup_inputs):
//   xyz (B,N,3) f32, new_xyz (B,P,3) f32, features (B,C,N) f32
//   out = concat([grouped_xyz - center, grouped_features], ch) -> (B, 3+C, P, S)
#define BB 2
#define NN 16384
#define PP 4096
#define CC 64
#define SS 32
#define R2 0.01f
#define OUTCH (3 + CC)
#define GRES 10
#define NCELL 1000  // 10x10x10, cell size 0.1 == radius
#define TILE 128    // samples per block in the fused kernel (4 queries x 32)

__device__ __forceinline__ int cell_of(float v) {
  int q = (int)(v * 10.0f);  // v in [0,1): floor
  return q < 0 ? 0 : (q > GRES - 1 ? GRES - 1 : q);
}
__device__ __forceinline__ int cell_clamp_floor(float v) {
  int q = (int)floorf(v * 10.0f);
  return q < 0 ? 0 : (q > GRES - 1 ? GRES - 1 : q);
}

// --------------------------------------------------------------------------
// Fused binning: one block per batch (1024 threads, 16 pts/thread).
// LDS histogram -> LDS shfl-scan -> scatter with LDS fill counters.
// Emits global CSR cellStart[] and sorted4[] = (x,y,z,idx_bits).
// Within-cell order is atomic-arrival (nondeterministic) but downstream
// output depends only on the SET of in-ball indices (bitmap) => determinism.
// --------------------------------------------------------------------------
__global__ __launch_bounds__(1024) void bin_kernel(
    const float* __restrict__ xyz, int* __restrict__ cellStartG,
    float4* __restrict__ sorted4) {
  __shared__ int hist[NCELL];
  __shared__ int fill[NCELL];
  __shared__ int cstart[NCELL];
  __shared__ int wtot[16];
  const int b = blockIdx.x;
  const int t = threadIdx.x;
  const int lane = t & 63;
  const int w = t >> 6;

  if (t < NCELL) { hist[t] = 0; fill[t] = 0; }
  __syncthreads();

  const float* __restrict__ xb = xyz + (size_t)b * NN * 3;
  int cells[16];
#pragma unroll
  for (int k = 0; k < 16; ++k) {
    const int i = t + k * 1024;
    const float x = xb[i * 3 + 0];
    const float y = xb[i * 3 + 1];
    const float z = xb[i * 3 + 2];
    const int c = (cell_of(z) * GRES + cell_of(y)) * GRES + cell_of(x);
    cells[k] = c;
    atomicAdd(&hist[c], 1);
  }
  __syncthreads();

  // exclusive scan over 1000 cells (threads 0..999; others add zeros)
  const int own = (t < NCELL) ? hist[t] : 0;
  int incl = own;
#pragma unroll
  for (int d = 1; d < 64; d <<= 1) {
    const int v = __shfl_up(incl, d);
    if (lane >= d) incl += v;
  }
  if (lane == 63) wtot[w] = incl;
  __syncthreads();
  int pre = 0;
#pragma unroll
  for (int k = 0; k < 16; ++k) pre += (k < w) ? wtot[k] : 0;
  const int excl = pre + incl - own;
  if (t < NCELL) {
    cstart[t] = excl;
    cellStartG[b * 1001 + t] = excl;
  }
  if (t == 0) cellStartG[b * 1001 + NCELL] = NN;
  __syncthreads();

#pragma unroll
  for (int k = 0; k < 16; ++k) {
    const int i = t + k * 1024;
    const float x = xb[i * 3 + 0];
    const float y = xb[i * 3 + 1];
    const float z = xb[i * 3 + 2];
    const int c = cells[k];
    const int r = atomicAdd(&fill[c], 1);
    float4 v;
    v.x = x; v.y = y; v.z = z; v.w = __int_as_float(i);
    sorted4[(size_t)b * NN + cstart[c] + r] = v;
  }
}

// --------------------------------------------------------------------------
// Transpose features (B,C,N) -> (B,N,C): gathers then read full 256B rows.
// --------------------------------------------------------------------------
__global__ __launch_bounds__(256) void transpose_feat_kernel(
    const float* __restrict__ feat, float* __restrict__ featT) {
  __shared__ float tile[64][65];
  const int n0 = blockIdx.x * 64;
  const int b = blockIdx.y;
  const int jn = threadIdx.x & 63;
  const int g4 = threadIdx.x >> 6;

  const float* fb = feat + (size_t)b * CC * NN;
#pragma unroll
  for (int k = 0; k < 16; ++k) {
    const int c = g4 * 16 + k;
    tile[c][jn] = fb[(size_t)c * NN + n0 + jn];
  }
  __syncthreads();
  float* ft = featT + ((size_t)b * NN + n0) * CC;
#pragma unroll
  for (int k = 0; k < 16; ++k) {
    const int j = g4 * 16 + k;
    ft[(size_t)j * CC + jn] = tile[jn][j];
  }
}

// --------------------------------------------------------------------------
// FUSED query + group. One block = 4 query-waves = TILE(128) samples.
//
// Phase Q (per wave): ball query via grid CSR. The <=9 row-ranges of the
// ball's cell box are flattened (lanes fetch bounds in parallel, shfl-scan
// concatenates) into one candidate space traversed in fully-packed 64-lane
// iterations. In-ball original indices marked in a per-wave 16384-bit LDS
// bitmap (9-word padded stripes => conflict-free); popcount + shfl-scan
// emits the first SS in ascending original-index order into LDS idxsm.
// Box margin +1e-5 can only ADD candidates (each exactly tested); d2 matches
// numpy bit-exactly (fp contract off, (dx^2+dy^2)+dz^2 order).
//
// Phase G: group_kernel_t body — stage 128 gathered featT rows (256B each)
// into LDS (stride 65 => conflict-free), write xyz-diff channels, then
// channel-major coalesced stores. Bitmap LDS is dead by then => reused.
// --------------------------------------------------------------------------
__global__ __launch_bounds__(256) void query_group_kernel(
    const float4* __restrict__ sorted4, const int* __restrict__ cellStart,
    const float* __restrict__ new_xyz, const float* __restrict__ xyz,
    const float* __restrict__ featT, float* __restrict__ out) {
#pragma clang fp contract(off)
  __shared__ float smem[TILE * 65];  // 33280 B; bitmap phase uses first 9216 B
  __shared__ int idxsm[TILE];
  const int widx = threadIdx.x >> 6;
  const int lane = threadIdx.x & 63;
  const int wave = blockIdx.x * 4 + widx;  // global query id
  const int b = wave >> 12;                // PP = 4096
  unsigned* bm = (unsigned*)smem + widx * 576;  // this wave's 512+pad words
  int* myout = idxsm + widx * SS;

  const float cx = new_xyz[wave * 3 + 0];
  const float cy = new_xyz[wave * 3 + 1];
  const float cz = new_xyz[wave * 3 + 2];
  const float4* __restrict__ sb = sorted4 + (size_t)b * NN;
  const int* __restrict__ csb = cellStart + b * 1001;

#pragma unroll
  for (int k = 0; k < 9; ++k) bm[k * 64 + lane] = 0;

  const float mg = 0.1f + 1e-5f;
  const int lox = cell_clamp_floor(cx - mg), hix = cell_clamp_floor(cx + mg);
  const int loy = cell_clamp_floor(cy - mg), hiy = cell_clamp_floor(cy + mg);
  const int loz = cell_clamp_floor(cz - mg), hiz = cell_clamp_floor(cz + mg);
  const int nx = hix - lox + 1;
  const int ny = hiy - loy + 1;
  const int nz = hiz - loz + 1;
  const int nr = nz * ny;  // 1..9 row-ranges

  // lanes 0..nr-1 fetch their range bounds in parallel
  int s_l = 0, len_l = 0;
  if (lane < nr) {
    int zi, yi;
    if (ny == 1) { zi = lane; yi = 0; }
    else if (ny == 2) { zi = lane >> 1; yi = lane & 1; }
    else { zi = (lane * 11) >> 5; yi = lane - zi * 3; }  // lane/3, lane<9
    const int c0 = ((loz + zi) * GRES + (loy + yi)) * GRES + lox;
    s_l = csb[c0];
    len_l = csb[c0 + nx] - s_l;
  }
  int incl = len_l;
#pragma unroll
  for (int d = 1; d <= 8; d <<= 1) {
    const int v = __shfl_up(incl, d);
    if (lane >= d) incl += v;
  }
  const int T = __shfl(incl, nr - 1);  // total candidates
  const int Lx = incl - len_l;         // exclusive offset of this range

  int Lk[9], Sk[9];
#pragma unroll
  for (int k = 0; k < 9; ++k) {  // Lk[k] == T for k >= nr
    Lk[k] = __shfl(Lx, k);
    Sk[k] = __shfl(s_l, k);
  }

  for (int t0 = 0; t0 < T; t0 += 64) {
    const int g = t0 + lane;
    if (g < T) {
      int L = Lk[0], S = Sk[0];
#pragma unroll
      for (int k = 1; k < 9; ++k) {
        const bool cge = g >= Lk[k];
        L = cge ? Lk[k] : L;
        S = cge ? Sk[k] : S;
      }
      const float4 pt = sb[S + (g - L)];
      const float dx = cx - pt.x;
      const float dy = cy - pt.y;
      const float dz = cz - pt.z;
      const float a = dx * dx + dy * dy;
      const float d2 = a + dz * dz;
      if (d2 < R2) {
        const int orig = __float_as_int(pt.w);
        const int wi = orig >> 5;  // word 0..511
        atomicOr(&bm[(wi >> 3) * 9 + (wi & 7)], 1u << (orig & 31));
      }
    }
  }
  __threadfence_block();  // drain LDS atomics before the scan reads

  // Scan: lane l owns words [8l,8l+8) = orig indices [256l, 256l+256).
  unsigned wv[8];
  int c = 0;
  int fi = INT_MAX;
#pragma unroll
  for (int k = 0; k < 8; ++k) {
    wv[k] = bm[lane * 9 + k];
    c += (int)__popc(wv[k]);
    if (fi == INT_MAX && wv[k])
      fi = lane * 256 + k * 32 + (int)__builtin_ctz(wv[k]);
  }

  int incl2 = c;
#pragma unroll
  for (int d = 1; d < 64; d <<= 1) {
    const int t = __shfl_up(incl2, d);
    if (lane >= d) incl2 += t;
  }
  const int E = incl2 - c;              // exclusive prefix
  const int total = __shfl(incl2, 63);  // wave total in-ball count

  const unsigned long long nb = __ballot(c > 0);
  int fc = 0;
  if (nb) fc = __shfl(fi, (int)__builtin_ctzll(nb));

  int s = E;
  if (s < SS) {
#pragma unroll
    for (int k = 0; k < 8; ++k) {
      unsigned ww = wv[k];
      while (ww && s < SS) {
        const int bpos = (int)__builtin_ctz(ww);
        ww &= ww - 1;
        myout[s++] = lane * 256 + k * 32 + bpos;
      }
      if (s >= SS) break;
    }
  }
  for (int s2 = total + lane; s2 < SS; s2 += 64) myout[s2] = fc;

  __syncthreads();  // idxsm complete for all 4 waves; bitmap LDS now dead

  // ---------------- Phase G: gather + group (base = this block's samples) --
  const int base = blockIdx.x * TILE;
  const int t = threadIdx.x;
  const size_t PS = (size_t)PP * SS;

  const float4* ftb = (const float4*)(featT + (size_t)b * NN * CC);
#pragma unroll
  for (int k = 0; k < 8; ++k) {
    const int u = k * 256 + t;  // [0, 2048)
    const int r = u >> 4;       // sample row 0..127
    const int q = u & 15;       // float4 within row
    const int v = idxsm[r];
    const float4 val = ftb[(size_t)v * 16 + q];
    float* dst = &smem[r * 65 + q * 4];
    dst[0] = val.x; dst[1] = val.y; dst[2] = val.z; dst[3] = val.w;
  }
  __syncthreads();

  if (t < TILE) {
    const int g = base + t;
    const int v = idxsm[t];
    const int p = (g >> 5) & (PP - 1);
    const float* xr = xyz + ((size_t)b * NN + v) * 3;
    const float* cr = new_xyz + (size_t)(b * PP + p) * 3;
    const size_t ob = (size_t)b * OUTCH * PS + ((size_t)g & (PS - 1));
    out[ob + 0 * PS] = xr[0] - cr[0];
    out[ob + 1 * PS] = xr[1] - cr[1];
    out[ob + 2 * PS] = xr[2] - cr[2];
  }

  float* ob3 = out + (size_t)b * OUTCH * PS + 3 * PS + ((size_t)base & (PS - 1));
#pragma unroll
  for (int k = 0; k < 32; ++k) {
    const int u = k * 256 + t;  // [0, 8192)
    const int c2 = u >> 7;      // channel 0..63
    const int r = u & 127;      // row 0..127
    ob3[(size_t)c2 * PS + r] = smem[r * 65 + c2];
  }
}

extern "C" void kernel_launch(void* const* d_in, const int* in_sizes, int n_in,
                              void* d_out, int out_size, void* d_ws, size_t ws_size,
                              hipStream_t stream) {
  const float* xyz = (const float*)d_in[0];
  const float* new_xyz = (const float*)d_in[1];
  const float* feat = (const float*)d_in[2];
  float* out = (float*)d_out;

  // ws layout (all regions live simultaneously during the fused kernel):
  //   [featT 8.39MB][sorted4 0.5MB][cellStart 8KB]
  float* featT = (float*)d_ws;
  const size_t featTBytes = (size_t)BB * NN * CC * sizeof(float);
  float4* sorted4 = (float4*)((char*)d_ws + featTBytes);
  int* cellStart = (int*)((char*)d_ws + featTBytes + (size_t)BB * NN * sizeof(float4));

  bin_kernel<<<BB, 1024, 0, stream>>>(xyz, cellStart, sorted4);
  transpose_feat_kernel<<<dim3(NN / 64, BB), 256, 0, stream>>>(feat, featT);
  query_group_kernel<<<(BB * PP) / 4, 256, 0, stream>>>(sorted4, cellStart,
                                                        new_xyz, xyz, featT, out);
}